// Round 9
// baseline (324.950 us; speedup 1.0000x reference)
//
#include <hip/hip_runtime.h>
#include <hip/hip_bf16.h>
#include <math.h>

#define Bn 4
#define Cn 64
#define Pn 4096   // 64*64
#define QT 128    // R21: q-tile per block (1024-thr blocks, 128 blocks total)
#define PBK 128   // p-block per flash iteration
#define NITER (Pn / PBK)
#define LOG2E 1.4426950408889634f

typedef __attribute__((ext_vector_type(8))) short short8;   // 8 bf16 (MFMA K=32 A/B frag)
typedef __attribute__((ext_vector_type(4))) short short4v;  // 4 bf16 (MFMA K=16 A/B frag)
typedef __attribute__((ext_vector_type(4))) float float4v;  // MFMA C/D frag
typedef __attribute__((ext_vector_type(2))) unsigned uint2v;
typedef unsigned short bfu;

__device__ __forceinline__ bfu f2bf(float x) {
    unsigned u = __float_as_uint(x);
    u = (u + 0x7fffu + ((u >> 16) & 1u)) >> 16;   // RNE; inputs finite
    return (bfu)u;
}

// ---------------------------------------------------------------------------
// Prep (unchanged): 768 blocks, 16KB LDS.
//   blocks [0,512):   knorm -> bf16 Kpc [B][P][C]  and tiled Kcp2 [B][P/16][C][16p]
//   blocks [512,768): 3x3 zero-padded box-sum * log2(e) -> S [B][C][P]
// ---------------------------------------------------------------------------
__global__ __launch_bounds__(256) void prep_kernel(const float* __restrict__ fg,
                                                   bfu* __restrict__ Kpc,
                                                   bfu* __restrict__ Kcp2,
                                                   float* __restrict__ S) {
    __shared__ float shbuf[64 * 64];
    int t = threadIdx.x;
    if (blockIdx.x < 512) {
        float* tile  = shbuf;            // [64c][32p] stride 33
        float* rnorm = shbuf + 64 * 33;
        int b  = blockIdx.x >> 7;
        int p0 = (blockIdx.x & 127) << 5;
        const float* src = fg + (size_t)b * Cn * Pn + p0;
        #pragma unroll
        for (int i = 0; i < 8; ++i) {
            int idx = i * 256 + t;
            int c = idx >> 5, p = idx & 31;
            tile[c * 33 + p] = src[(size_t)c * Pn + p];
        }
        __syncthreads();
        if (t < 32) {
            float ss = 0.f;
            #pragma unroll
            for (int c = 0; c < 64; ++c) { float v = tile[c * 33 + t]; ss += v * v; }
            rnorm[t] = 1.0f / (sqrtf(ss) + 1e-8f);
        }
        __syncthreads();
        bfu* dpc = Kpc + ((size_t)b * Pn + p0) * Cn;
        #pragma unroll
        for (int i = 0; i < 8; ++i) {
            int idx = i * 256 + t;
            int p = idx >> 6, c = idx & 63;
            dpc[(size_t)p * Cn + c] = f2bf(tile[c * 33 + p] * rnorm[p]);
        }
        // tiled transpose layout: Kcp2[b][pt][c][pl], pt = p>>4, pl = p&15
        bfu* d2 = Kcp2 + ((size_t)b * 256 + (p0 >> 4)) * 1024;
        #pragma unroll
        for (int i = 0; i < 8; ++i) {
            int idx = i * 256 + t;
            int c = idx >> 5, p = idx & 31;
            d2[(size_t)(p >> 4) * 1024 + c * 16 + (p & 15)] =
                f2bf(tile[c * 33 + p] * rnorm[p]);
        }
    } else {
        float (*pl)[64] = (float(*)[64])shbuf;
        int bc = blockIdx.x - 512;
        const float* src = fg + (size_t)bc * Pn;
        float*       dst = S  + (size_t)bc * Pn;
        #pragma unroll
        for (int i = 0; i < 16; ++i) {
            int idx = i * 256 + t;
            pl[idx >> 6][idx & 63] = src[idx];
        }
        __syncthreads();
        #pragma unroll
        for (int i = 0; i < 16; ++i) {
            int idx = i * 256 + t;
            int h = idx >> 6, w = idx & 63;
            float s = 0.f;
            #pragma unroll
            for (int dh = -1; dh <= 1; ++dh) {
                int hh = h + dh;
                if (hh < 0 || hh >= 64) continue;
                #pragma unroll
                for (int dw = -1; dw <= 1; ++dw) {
                    int ww = w + dw;
                    if (ww < 0 || ww >= 64) continue;
                    s += pl[hh][ww];
                }
            }
            dst[idx] = s * LOG2E;
        }
    }
}

// ---------------------------------------------------------------------------
// Flash (R21). QT=128, 128 blocks x 1024 thr (16 waves). Issue-bound fix:
//  - 16-wave blocks force 4 waves/SIMD co-residency; waves w and w+8 issue
//    IDENTICAL A/T loads (different q-halves of S) -> L1 dedup, and total
//    read traffic halves to 128MB.
//  - cvt_pk_bf16_f32 pack (R17-verified) removes ~60 VALU/iter.
//  - #pragma unroll 2 (R18-verified) renames away the operand rotate.
// Group g = w>>3 owns q-range [q0+64g, q0+64g+64); wave pw = w&7 owns p-rows
// [16pw,16pw+16) of each 128-p block. K-loop otherwise identical to the R0
// champion: zero LDS, no barriers, register prefetch one iteration ahead.
// ---------------------------------------------------------------------------
__global__ __launch_bounds__(1024, 4) void flash_kernel(const bfu* __restrict__ Kpc,
                                                        const bfu* __restrict__ Kcp2,
                                                        const float* __restrict__ S,
                                                        float* __restrict__ out) {
    // Sl bf16 [128q][64c] (16KB) lives at offset 0; epilogue overlays the
    // whole region with two Ol buffers: fp32 [2 groups][4][64c][66] = 135168 B.
    __shared__ __align__(16) unsigned char smem[135168];
    __shared__ float wredl[16][64];
    bfu* Sl = (bfu*)smem;

    int i  = blockIdx.x;                         // [0,128)
    int b  = (i & 7) >> 1;                       // XCD-pair locality
    int qt = ((i >> 3) << 1) | (i & 1);          // [0,32)
    int q0 = qt * QT;
    int t  = threadIdx.x;
    int w = t >> 6, l = t & 63, lq = l & 15, quad = l >> 4;
    int g = w >> 3, pw = w & 7;                  // q-group, p-row owner

    const float* Sg  = S    + (size_t)b * Cn * Pn;
    const bfu*   gpc = Kpc  + (size_t)b * Pn * Cn;
    const bfu*   gt  = Kcp2 + (size_t)b * 256 * 1024;   // [pt][c][pl]

    // Sl[q][c] = bf16(Sg[c][q0+q]) (S pre-scaled by log2e), XOR-swizzled rows
    {
        int c = t >> 4, qq = (t & 15) * 8;
        const float* sp = &Sg[(size_t)c * Pn + q0 + qq];
        float4 v0 = *(const float4*)sp;
        float4 v1 = *(const float4*)(sp + 4);
        float vv[8] = {v0.x, v0.y, v0.z, v0.w, v1.x, v1.y, v1.z, v1.w};
        int ch = c >> 3, cl = c & 7;
        #pragma unroll
        for (int k = 0; k < 8; ++k) {
            int row = qq + k;
            Sl[row * 64 + ((ch ^ (row & 7)) << 3) + cl] = f2bf(vv[k]);
        }
    }
    __syncthreads();   // Sl visible

    // hoist S B-frags for this wave's q-group: row = g*64 + nt*16 + lq
    short8 bs[4][2];
    #pragma unroll
    for (int nt = 0; nt < 4; ++nt)
        #pragma unroll
        for (int ks = 0; ks < 2; ++ks) {
            int row = g * 64 + nt * 16 + lq;
            bs[nt][ks] = *(const short8*)&Sl[row * 64 + (((ks * 4 + quad) ^ (lq & 7)) << 3)];
        }

    float4v o[4][4];   // [nt][cb]: q = 64g+16nt+4quad+r, c = 16cb+lq
    #pragma unroll
    for (int nt = 0; nt < 4; ++nt)
        #pragma unroll
        for (int cb = 0; cb < 4; ++cb) o[nt][cb] = (float4v){0.f, 0.f, 0.f, 0.f};
    float lacc[4] = {0.f, 0.f, 0.f, 0.f};

    // per-wave global addresses (identical for waves w and w+8 -> L1 dedup)
    const bfu* ap = gpc + ((size_t)16 * pw + lq) * Cn + quad * 8;          // score A rows
    const bfu* tp = gt + (size_t)pw * 1024 + lq * 16 + quad * 4;           // accum B frags

    // prologue: load pb=0 operands
    float4 a0 = *(const float4*)ap;
    float4 a1 = *(const float4*)(ap + 32);
    short4v kb[4];
    #pragma unroll
    for (int cb = 0; cb < 4; ++cb) kb[cb] = *(const short4v*)(tp + cb * 256);

    #pragma unroll 2
    for (int pb = 0; pb < NITER; ++pb) {
        // ---- prefetch pb+1 operands ----
        float4 na0, na1;
        short4v nkb[4];
        if (pb + 1 < NITER) {
            const bfu* apn = ap + (size_t)(pb + 1) * PBK * Cn;
            na0 = *(const float4*)apn;
            na1 = *(const float4*)(apn + 32);
            const bfu* tpn = tp + (size_t)(pb + 1) * 8 * 1024;
            #pragma unroll
            for (int cb = 0; cb < 4; ++cb) nkb[cb] = *(const short4v*)(tpn + cb * 256);
        }

        // ---- score GEMM (K=32): D[m=p][n=q], 4 q-subtiles ----
        short8 af0 = *(short8*)&a0, af1 = *(short8*)&a1;
        float4v sc[4];
        #pragma unroll
        for (int nt = 0; nt < 4; ++nt) {
            float4v acc = (float4v){0.f, 0.f, 0.f, 0.f};
            acc = __builtin_amdgcn_mfma_f32_16x16x32_bf16(af0, bs[nt][0], acc, 0, 0, 0);
            acc = __builtin_amdgcn_mfma_f32_16x16x32_bf16(af1, bs[nt][1], acc, 0, 0, 0);
            sc[nt] = acc;
        }

        // ---- exp2 + denominator; cvt_pk packs E as K=16 A-frags ----
        short4v epk[4];
        #pragma unroll
        for (int nt = 0; nt < 4; ++nt) {
            float e0 = __builtin_amdgcn_exp2f(sc[nt][0]);
            float e1 = __builtin_amdgcn_exp2f(sc[nt][1]);
            float e2 = __builtin_amdgcn_exp2f(sc[nt][2]);
            float e3 = __builtin_amdgcn_exp2f(sc[nt][3]);
            lacc[nt] += (e0 + e1) + (e2 + e3);
            unsigned plo, phi;
            asm("v_cvt_pk_bf16_f32 %0, %1, %2" : "=v"(plo) : "v"(e0), "v"(e1));
            asm("v_cvt_pk_bf16_f32 %0, %1, %2" : "=v"(phi) : "v"(e2), "v"(e3));
            uint2v pk2 = {plo, phi};
            epk[nt] = __builtin_bit_cast(short4v, pk2);
        }

        // ---- accum GEMM (K=16): o'[q][c] += E · Kcp2 frags ----
        #pragma unroll
        for (int cb = 0; cb < 4; ++cb) {
            #pragma unroll
            for (int nt = 0; nt < 4; ++nt)
                o[nt][cb] = __builtin_amdgcn_mfma_f32_16x16x16bf16_1k(epk[nt], kb[cb], o[nt][cb], 0, 0, 0);
        }

        // rotate prefetched operands (renamed away by unroll 2)
        a0 = na0; a1 = na1;
        #pragma unroll
        for (int cb = 0; cb < 4; ++cb) kb[cb] = nkb[cb];
    }

    // ---- denominator: quad-reduce then stash per wave ----
    #pragma unroll
    for (int nt = 0; nt < 4; ++nt) {
        lacc[nt] += __shfl_xor(lacc[nt], 16);
        lacc[nt] += __shfl_xor(lacc[nt], 32);
    }
    if (quad == 0)
        #pragma unroll
        for (int nt = 0; nt < 4; ++nt) wredl[w][nt * 16 + lq] = lacc[nt];

    // ---- cross-wave combine via LDS overlay, per q-group (2 rounds) ----
    float* Ol  = (float*)smem;            // [2 groups][4][64 c][66] fp32
    float* Olg = Ol + g * 16896;          // this group's 67584-B region
    int lw = w & 7;
    __syncthreads();            // K-loops done; Sl dead; wredl visible
    if (lw < 4) {
        #pragma unroll
        for (int nt = 0; nt < 4; ++nt)
            #pragma unroll
            for (int cb = 0; cb < 4; ++cb)
                #pragma unroll
                for (int r = 0; r < 4; ++r)
                    Olg[(lw * 64 + 16 * cb + lq) * 66 + nt * 16 + quad * 4 + r] = o[nt][cb][r];
    }
    __syncthreads();
    if (lw >= 4) {
        #pragma unroll
        for (int nt = 0; nt < 4; ++nt)
            #pragma unroll
            for (int cb = 0; cb < 4; ++cb)
                #pragma unroll
                for (int r = 0; r < 4; ++r)
                    Olg[((lw - 4) * 64 + 16 * cb + lq) * 66 + nt * 16 + quad * 4 + r] += o[nt][cb][r];
    }
    __syncthreads();

    // ---- final: out[c][q0+q] = sum of 4 buffers / l_q  (q in [0,128)) ----
    float* og = out + (size_t)b * Cn * Pn;
    #pragma unroll
    for (int k = 0; k < 8; ++k) {
        int idx = k * 1024 + t;
        int c = idx >> 7, q = idx & 127;
        int g2 = q >> 6, ql = q & 63;
        const float* O2 = Ol + g2 * 16896;
        float lsum = ((wredl[g2 * 8 + 0][ql] + wredl[g2 * 8 + 1][ql]) +
                      (wredl[g2 * 8 + 2][ql] + wredl[g2 * 8 + 3][ql])) +
                     ((wredl[g2 * 8 + 4][ql] + wredl[g2 * 8 + 5][ql]) +
                      (wredl[g2 * 8 + 6][ql] + wredl[g2 * 8 + 7][ql]));
        float v = ((O2[c * 66 + ql] + O2[(64 + c) * 66 + ql]) +
                   (O2[(128 + c) * 66 + ql] + O2[(192 + c) * 66 + ql])) / lsum;
        og[(size_t)c * Pn + q0 + q] = v;
    }
}

// ---------------------------------------------------------------------------
extern "C" void kernel_launch(void* const* d_in, const int* in_sizes, int n_in,
                              void* d_out, int out_size, void* d_ws, size_t ws_size,
                              hipStream_t stream) {
    const float* fg = (const float*)d_in[0];
    float* out = (float*)d_out;
    bfu*   Kpc  = (bfu*)d_ws;                              // 2 MB  bf16 [B][P][C]
    bfu*   Kcp2 = Kpc + (size_t)Bn * Pn * Cn;              // 2 MB  bf16 [B][P/16][C][16]
    float* S    = (float*)(Kcp2 + (size_t)Bn * Pn * Cn);   // 4 MB  fp32 [B][C][P] (pre-scaled by log2e)

    prep_kernel <<<768, 256, 0, stream>>>(fg, Kpc, Kcp2, S);
    flash_kernel<<<128, 1024, 0, stream>>>(Kpc, Kcp2, S, out);
}